// Round 1
// baseline (294.635 us; speedup 1.0000x reference)
//
#include <hip/hip_runtime.h>
#include <stdint.h>

// ---------------------------------------------------------------------------
// kWTA: threshold = K-th largest of N fp32; out[i] = in[i] < thr ? 0 : in[i]
//
// Device-side exact radix select (k arrives as a device scalar):
//   K1: 4096-bin LDS histogram of top-12 bits of order-preserving key
//   K2: single-block suffix scan -> bucket containing K-th, k' within bucket
//   K3: gather candidate keys (elements in that bucket) into ws
//   K4: single-block bitwise radix select over remaining 20 bits -> exact thr
//   K5: apply pass (float4)
// ---------------------------------------------------------------------------

#define HIST_BINS 4096
#define CTRL_OFF  HIST_BINS        // word offset of control block in ws
#define CAND_OFF  (HIST_BINS + 16) // word offset of candidate buffer
// ctrl[0] = gather counter, ctrl[1] = selected bucket,
// ctrl[2] = k' (rank within bucket, 1-based), ctrl[3] = threshold float bits

__device__ __forceinline__ uint32_t f2key(float x) {
  uint32_t u = __float_as_uint(x);
  return (u & 0x80000000u) ? ~u : (u | 0x80000000u);  // larger key <=> larger float
}
__device__ __forceinline__ float key2f(uint32_t k) {
  uint32_t u = (k & 0x80000000u) ? (k & 0x7fffffffu) : ~k;
  return __uint_as_float(u);
}

__global__ void k_hist(const float4* __restrict__ in, int n4, int ntail,
                       const float* __restrict__ in_s,
                       uint32_t* __restrict__ ghist) {
  __shared__ uint32_t lh[HIST_BINS];
  for (int i = threadIdx.x; i < HIST_BINS; i += blockDim.x) lh[i] = 0;
  __syncthreads();
  int stride = gridDim.x * blockDim.x;
  for (int i = blockIdx.x * blockDim.x + threadIdx.x; i < n4; i += stride) {
    float4 v = in[i];
    atomicAdd(&lh[f2key(v.x) >> 20], 1u);
    atomicAdd(&lh[f2key(v.y) >> 20], 1u);
    atomicAdd(&lh[f2key(v.z) >> 20], 1u);
    atomicAdd(&lh[f2key(v.w) >> 20], 1u);
  }
  if (blockIdx.x == 0 && (int)threadIdx.x < ntail)  // scalar tail (n % 4)
    atomicAdd(&lh[f2key(in_s[n4 * 4 + threadIdx.x]) >> 20], 1u);
  __syncthreads();
  for (int i = threadIdx.x; i < HIST_BINS; i += blockDim.x) {
    uint32_t c = lh[i];
    if (c) atomicAdd(&ghist[i], c);
  }
}

__global__ void k_select_bucket(const uint32_t* __restrict__ gh,
                                const int* __restrict__ kptr,
                                uint32_t* __restrict__ ctrl) {
  __shared__ uint32_t chunk[256];
  const int CPT = HIST_BINS / 256;  // 16 bins per thread
  int t = threadIdx.x;
  uint32_t s = 0;
  for (int i = 0; i < CPT; i++) s += gh[t * CPT + i];
  chunk[t] = s;
  __syncthreads();
  if (t == 0) {
    uint32_t K = (uint32_t)kptr[0];
    uint32_t above = 0;
    int sel = 0;
    for (int c = 255; c >= 0; c--) {
      if (above + chunk[c] >= K) { sel = c; break; }
      above += chunk[c];
    }
    int bsel = sel * CPT;
    for (int b = sel * CPT + CPT - 1; b >= sel * CPT; b--) {
      uint32_t c = gh[b];
      if (above + c >= K) { bsel = b; break; }
      above += c;
    }
    ctrl[1] = (uint32_t)bsel;
    ctrl[2] = K - above;  // 1-based rank within bucket (from the top)
  }
}

__global__ void k_gather(const float4* __restrict__ in, int n4, int ntail,
                         const float* __restrict__ in_s,
                         uint32_t* __restrict__ ctrl,
                         uint32_t* __restrict__ cands, uint32_t cap) {
  uint32_t sel = ctrl[1];
  int stride = gridDim.x * blockDim.x;
  for (int i = blockIdx.x * blockDim.x + threadIdx.x; i < n4; i += stride) {
    float4 v = in[i];
    uint32_t k0 = f2key(v.x), k1 = f2key(v.y), k2 = f2key(v.z), k3 = f2key(v.w);
    if ((k0 >> 20) == sel) { uint32_t p = atomicAdd(&ctrl[0], 1u); if (p < cap) cands[p] = k0; }
    if ((k1 >> 20) == sel) { uint32_t p = atomicAdd(&ctrl[0], 1u); if (p < cap) cands[p] = k1; }
    if ((k2 >> 20) == sel) { uint32_t p = atomicAdd(&ctrl[0], 1u); if (p < cap) cands[p] = k2; }
    if ((k3 >> 20) == sel) { uint32_t p = atomicAdd(&ctrl[0], 1u); if (p < cap) cands[p] = k3; }
  }
  if (blockIdx.x == 0 && (int)threadIdx.x < ntail) {
    uint32_t kk = f2key(in_s[n4 * 4 + threadIdx.x]);
    if ((kk >> 20) == sel) { uint32_t p = atomicAdd(&ctrl[0], 1u); if (p < cap) cands[p] = kk; }
  }
}

__global__ void __launch_bounds__(1024) k_final(uint32_t* __restrict__ ctrl,
                                                const uint32_t* __restrict__ cands,
                                                uint32_t cap) {
  __shared__ uint32_t sh[8192];
  __shared__ uint32_t red[16];
  __shared__ uint32_t s_p, s_want;
  int t = threadIdx.x;
  uint32_t n = ctrl[0]; if (n > cap) n = cap;
  bool useLds = (n <= 8192);
  if (useLds) for (uint32_t i = t; i < n; i += blockDim.x) sh[i] = cands[i];
  if (t == 0) { s_p = ctrl[1] << 20; s_want = ctrl[2]; }
  __syncthreads();
  uint32_t p = s_p, want = s_want;
  for (int bit = 19; bit >= 0; bit--) {
    uint32_t test = p | (1u << bit);
    uint32_t hi = test >> bit;
    uint32_t cnt = 0;
    for (uint32_t i = t; i < n; i += blockDim.x) {
      uint32_t kk = useLds ? sh[i] : cands[i];
      cnt += ((kk >> bit) == hi) ? 1u : 0u;
    }
    for (int off = 32; off; off >>= 1) cnt += __shfl_down((int)cnt, off);
    int wave = t >> 6, lane = t & 63;
    if (lane == 0) red[wave] = cnt;
    __syncthreads();
    if (t == 0) {
      uint32_t tot = 0;
      for (int w = 0; w < 16; w++) tot += red[w];
      if (tot >= want) p = test; else want -= tot;
      s_p = p; s_want = want;
    }
    __syncthreads();
    p = s_p; want = s_want;
  }
  if (t == 0) ctrl[3] = __float_as_uint(key2f(p));
}

__global__ void k_apply(const float4* __restrict__ in, float4* __restrict__ out,
                        int n4, int ntail,
                        const float* __restrict__ in_s, float* __restrict__ out_s,
                        const uint32_t* __restrict__ ctrl) {
  float thr = __uint_as_float(ctrl[3]);
  int stride = gridDim.x * blockDim.x;
  for (int i = blockIdx.x * blockDim.x + threadIdx.x; i < n4; i += stride) {
    float4 v = in[i];
    v.x = (v.x < thr) ? 0.0f : v.x;
    v.y = (v.y < thr) ? 0.0f : v.y;
    v.z = (v.z < thr) ? 0.0f : v.z;
    v.w = (v.w < thr) ? 0.0f : v.w;
    out[i] = v;
  }
  if (blockIdx.x == 0 && (int)threadIdx.x < ntail) {
    float x = in_s[n4 * 4 + threadIdx.x];
    out_s[n4 * 4 + threadIdx.x] = (x < thr) ? 0.0f : x;
  }
}

extern "C" void kernel_launch(void* const* d_in, const int* in_sizes, int n_in,
                              void* d_out, int out_size, void* d_ws, size_t ws_size,
                              hipStream_t stream) {
  const float* in = (const float*)d_in[0];
  const int* kptr = (const int*)d_in[1];
  float* out = (float*)d_out;
  int n = in_sizes[0];
  int n4 = n >> 2;
  int ntail = n & 3;

  uint32_t* ws = (uint32_t*)d_ws;
  uint32_t* ghist = ws;
  uint32_t* ctrl = ws + CTRL_OFF;
  uint32_t* cands = ws + CAND_OFF;
  uint32_t cap = 0;
  size_t ws_words = ws_size / 4;
  if (ws_words > CAND_OFF) cap = (uint32_t)(ws_words - CAND_OFF);

  // zero histogram + control block (ws is poisoned 0xAA before each launch)
  hipMemsetAsync(d_ws, 0, (CAND_OFF) * sizeof(uint32_t), stream);

  k_hist<<<1024, 256, 0, stream>>>((const float4*)in, n4, ntail, in, ghist);
  k_select_bucket<<<1, 256, 0, stream>>>(ghist, kptr, ctrl);
  k_gather<<<1024, 256, 0, stream>>>((const float4*)in, n4, ntail, in, ctrl, cands, cap);
  k_final<<<1, 1024, 0, stream>>>(ctrl, cands, cap);
  k_apply<<<4096, 256, 0, stream>>>((const float4*)in, (float4*)out, n4, ntail,
                                    in, out, ctrl);
}

// Round 2
// 274.101 us; speedup vs baseline: 1.0749x; 1.0749x over previous
//
#include <hip/hip_runtime.h>
#include <stdint.h>

// ---------------------------------------------------------------------------
// kWTA: threshold = K-th largest of N fp32; out[i] = in[i] < thr ? 0 : in[i]
//
// Exact device-side radix select, 4 kernels:
//   K1: 4096-bin LDS histogram of top-12 bits of order-preserving key
//   K2: single-block suffix scan -> bucket containing K-th, k' within bucket
//   K3: fused apply+gather: above-bucket -> copy, below -> 0, in-bucket ->
//       provisional 0 + push (key,idx) to candidate list
//   K4: single-block bitwise radix select over remaining 20 bits -> exact
//       threshold; scatter-restore the in-bucket winners
// ---------------------------------------------------------------------------

#define HIST_BINS 4096
#define CTRL_OFF  HIST_BINS        // word offset of control block in ws
#define CAND_OFF  (HIST_BINS + 16) // word offset of candidate buffers
// ctrl[0] = gather counter, ctrl[1] = selected bucket,
// ctrl[2] = k' (rank within bucket, 1-based), ctrl[3] = threshold float bits

__device__ __forceinline__ uint32_t f2key(float x) {
  uint32_t u = __float_as_uint(x);
  return (u & 0x80000000u) ? ~u : (u | 0x80000000u);  // larger key <=> larger float
}
__device__ __forceinline__ float key2f(uint32_t k) {
  uint32_t u = (k & 0x80000000u) ? (k & 0x7fffffffu) : ~k;
  return __uint_as_float(u);
}

__global__ void k_hist(const float4* __restrict__ in, int n4, int ntail,
                       const float* __restrict__ in_s,
                       uint32_t* __restrict__ ghist) {
  __shared__ uint32_t lh[HIST_BINS];
  for (int i = threadIdx.x; i < HIST_BINS; i += blockDim.x) lh[i] = 0;
  __syncthreads();
  int stride = gridDim.x * blockDim.x;
  for (int i = blockIdx.x * blockDim.x + threadIdx.x; i < n4; i += stride) {
    float4 v = in[i];
    atomicAdd(&lh[f2key(v.x) >> 20], 1u);
    atomicAdd(&lh[f2key(v.y) >> 20], 1u);
    atomicAdd(&lh[f2key(v.z) >> 20], 1u);
    atomicAdd(&lh[f2key(v.w) >> 20], 1u);
  }
  if (blockIdx.x == 0 && (int)threadIdx.x < ntail)  // scalar tail (n % 4)
    atomicAdd(&lh[f2key(in_s[n4 * 4 + threadIdx.x]) >> 20], 1u);
  __syncthreads();
  for (int i = threadIdx.x; i < HIST_BINS; i += blockDim.x) {
    uint32_t c = lh[i];
    if (c) atomicAdd(&ghist[i], c);
  }
}

__global__ void k_select_bucket(const uint32_t* __restrict__ gh,
                                const int* __restrict__ kptr,
                                uint32_t* __restrict__ ctrl) {
  __shared__ uint32_t chunk[256];
  const int CPT = HIST_BINS / 256;  // 16 bins per thread
  int t = threadIdx.x;
  uint32_t s = 0;
  for (int i = 0; i < CPT; i++) s += gh[t * CPT + i];
  chunk[t] = s;
  __syncthreads();
  if (t == 0) {
    uint32_t K = (uint32_t)kptr[0];
    uint32_t above = 0;
    int sel = 0;
    for (int c = 255; c >= 0; c--) {
      if (above + chunk[c] >= K) { sel = c; break; }
      above += chunk[c];
    }
    int bsel = sel * CPT;
    for (int b = sel * CPT + CPT - 1; b >= sel * CPT; b--) {
      uint32_t c = gh[b];
      if (above + c >= K) { bsel = b; break; }
      above += c;
    }
    ctrl[1] = (uint32_t)bsel;
    ctrl[2] = K - above;  // 1-based rank within bucket (from the top)
  }
}

// Fused apply + gather: definite elements written immediately; threshold-bucket
// elements provisionally zeroed and recorded (key, flat index) for K4's fixup.
__global__ void k_apply_gather(const float4* __restrict__ in,
                               float4* __restrict__ out, int n4, int ntail,
                               const float* __restrict__ in_s,
                               float* __restrict__ out_s,
                               uint32_t* __restrict__ ctrl,
                               uint32_t* __restrict__ keys,
                               uint32_t* __restrict__ idxs, uint32_t cap) {
  uint32_t sel = ctrl[1];
  int stride = gridDim.x * blockDim.x;
  for (int i = blockIdx.x * blockDim.x + threadIdx.x; i < n4; i += stride) {
    float4 v = in[i];
    uint32_t k0 = f2key(v.x), k1 = f2key(v.y), k2 = f2key(v.z), k3 = f2key(v.w);
    uint32_t b0 = k0 >> 20, b1 = k1 >> 20, b2 = k2 >> 20, b3 = k3 >> 20;
    float4 r;
    r.x = (b0 > sel) ? v.x : 0.0f;
    r.y = (b1 > sel) ? v.y : 0.0f;
    r.z = (b2 > sel) ? v.z : 0.0f;
    r.w = (b3 > sel) ? v.w : 0.0f;
    if (b0 == sel) { uint32_t p = atomicAdd(&ctrl[0], 1u); if (p < cap) { keys[p] = k0; idxs[p] = 4u * i + 0u; } }
    if (b1 == sel) { uint32_t p = atomicAdd(&ctrl[0], 1u); if (p < cap) { keys[p] = k1; idxs[p] = 4u * i + 1u; } }
    if (b2 == sel) { uint32_t p = atomicAdd(&ctrl[0], 1u); if (p < cap) { keys[p] = k2; idxs[p] = 4u * i + 2u; } }
    if (b3 == sel) { uint32_t p = atomicAdd(&ctrl[0], 1u); if (p < cap) { keys[p] = k3; idxs[p] = 4u * i + 3u; } }
    __builtin_nontemporal_store(r.x, &((float*)&out[i])[0]);
    __builtin_nontemporal_store(r.y, &((float*)&out[i])[1]);
    __builtin_nontemporal_store(r.z, &((float*)&out[i])[2]);
    __builtin_nontemporal_store(r.w, &((float*)&out[i])[3]);
  }
  if (blockIdx.x == 0 && (int)threadIdx.x < ntail) {
    int j = n4 * 4 + threadIdx.x;
    float x = in_s[j];
    uint32_t kk = f2key(x);
    uint32_t bb = kk >> 20;
    out_s[j] = (bb > sel) ? x : 0.0f;
    if (bb == sel) { uint32_t p = atomicAdd(&ctrl[0], 1u); if (p < cap) { keys[p] = kk; idxs[p] = (uint32_t)j; } }
  }
}

// Exact 20-bit radix select over the candidates, then scatter-restore winners.
__global__ void __launch_bounds__(1024) k_final(uint32_t* __restrict__ ctrl,
                                                const uint32_t* __restrict__ keys,
                                                const uint32_t* __restrict__ idxs,
                                                uint32_t cap,
                                                float* __restrict__ out_s) {
  __shared__ uint32_t sh[8192];
  __shared__ uint32_t red[16];
  __shared__ uint32_t s_p, s_want;
  int t = threadIdx.x;
  uint32_t n = ctrl[0]; if (n > cap) n = cap;
  bool useLds = (n <= 8192);
  if (useLds) for (uint32_t i = t; i < n; i += blockDim.x) sh[i] = keys[i];
  if (t == 0) { s_p = ctrl[1] << 20; s_want = ctrl[2]; }
  __syncthreads();
  uint32_t p = s_p, want = s_want;
  for (int bit = 19; bit >= 0; bit--) {
    uint32_t test = p | (1u << bit);
    uint32_t hi = test >> bit;
    uint32_t cnt = 0;
    for (uint32_t i = t; i < n; i += blockDim.x) {
      uint32_t kk = useLds ? sh[i] : keys[i];
      cnt += ((kk >> bit) == hi) ? 1u : 0u;
    }
    for (int off = 32; off; off >>= 1) cnt += __shfl_down((int)cnt, off);
    int wave = t >> 6, lane = t & 63;
    if (lane == 0) red[wave] = cnt;
    __syncthreads();
    if (t == 0) {
      uint32_t tot = 0;
      for (int w = 0; w < 16; w++) tot += red[w];
      if (tot >= want) p = test; else want -= tot;
      s_p = p; s_want = want;
    }
    __syncthreads();
    p = s_p; want = s_want;
  }
  if (t == 0) ctrl[3] = __float_as_uint(key2f(p));
  // fixup: restore in-bucket elements at or above the exact threshold
  for (uint32_t i = t; i < n; i += blockDim.x) {
    uint32_t kk = useLds ? sh[i] : keys[i];
    if (kk >= p) out_s[idxs[i]] = key2f(kk);
  }
}

extern "C" void kernel_launch(void* const* d_in, const int* in_sizes, int n_in,
                              void* d_out, int out_size, void* d_ws, size_t ws_size,
                              hipStream_t stream) {
  const float* in = (const float*)d_in[0];
  const int* kptr = (const int*)d_in[1];
  float* out = (float*)d_out;
  int n = in_sizes[0];
  int n4 = n >> 2;
  int ntail = n & 3;

  uint32_t* ws = (uint32_t*)d_ws;
  uint32_t* ghist = ws;
  uint32_t* ctrl = ws + CTRL_OFF;
  size_t ws_words = ws_size / 4;
  uint32_t cap = 0;
  if (ws_words > CAND_OFF + 2) cap = (uint32_t)((ws_words - CAND_OFF) / 2);
  uint32_t* keys = ws + CAND_OFF;
  uint32_t* idxs = keys + cap;

  // zero histogram + control block (ws is poisoned 0xAA before each launch)
  hipMemsetAsync(d_ws, 0, CAND_OFF * sizeof(uint32_t), stream);

  k_hist<<<1024, 256, 0, stream>>>((const float4*)in, n4, ntail, in, ghist);
  k_select_bucket<<<1, 256, 0, stream>>>(ghist, kptr, ctrl);
  k_apply_gather<<<4096, 256, 0, stream>>>((const float4*)in, (float4*)out,
                                           n4, ntail, in, out, ctrl, keys, idxs, cap);
  k_final<<<1, 1024, 0, stream>>>(ctrl, keys, idxs, cap, out);
}